// Round 16
// baseline (400.810 us; speedup 1.0000x reference)
//
#include <hip/hip_runtime.h>
#include <hip/hip_cooperative_groups.h>

namespace cg = cooperative_groups;

#define NN 50000
#define NE 1600000
#define NG 512
#define IN_DIM 128
#define HID 64

#define NB 128                       // nodes per bucket
#define NBK ((NN + NB - 1) / NB)     // 391 buckets
#define EBLK 512                     // edge-pass blocks
#define EPB (NE / EBLK)              // 3125 edges per block

typedef unsigned short ushort_t;
typedef unsigned int uint_t;

// float -> bf16 (RNE)
static __device__ __forceinline__ ushort_t f2bf(float f) {
    uint_t u = __float_as_uint(f);
    u += 0x7FFFu + ((u >> 16) & 1u);
    return (ushort_t)(u >> 16);
}
static __device__ __forceinline__ float bflo(uint_t u) { return __uint_as_float(u << 16); }
static __device__ __forceinline__ float bfhi(uint_t u) { return __uint_as_float(u & 0xFFFF0000u); }

// ---- fused build: cnt -> bscan -> tscan -> scatter -> binfo2 (1 coop kernel) ----
__global__ void build_kernel(const int* __restrict__ ei, const float* __restrict__ ea,
                             int* __restrict__ pcnt, int* __restrict__ tot,
                             int* __restrict__ bbase, int* __restrict__ indeg,
                             float* __restrict__ dis, int* __restrict__ offs,
                             int2* __restrict__ recs, int2* __restrict__ csr) {
    cg::grid_group grid = cg::this_grid();
    int b = blockIdx.x;          // 0..EBLK-1
    int tid = threadIdx.x;       // 0..255

    __shared__ int h[NBK];           // P1 histogram / P4 cursors
    __shared__ int s[256];           // P2/P3 scans
    __shared__ float degs[NB];       // P5
    __shared__ int cnts[NB];
    __shared__ int sc[NB];
    __shared__ int curs[NB];
    __shared__ float wdst[NB];

    // ---- P1: per-block coarse histogram of dst>>7 ----
    for (int i = tid; i < NBK; i += 256) h[i] = 0;
    __syncthreads();
    {
        int base = b * EPB;
        for (int e = base + tid; e < base + EPB; e += 256)
            atomicAdd(&h[ei[NE + e] >> 7], 1);
    }
    __syncthreads();
    for (int i = tid; i < NBK; i += 256)
        pcnt[(size_t)i * EBLK + b] = h[i];
    grid.sync();

    // ---- P2: per-bucket exclusive scan over EBLK partials (2 elems/thread) ----
    if (b < NBK) {
        size_t base = (size_t)b * EBLK;
        int v0 = pcnt[base + 2 * tid];
        int v1 = pcnt[base + 2 * tid + 1];
        int pairsum = v0 + v1;
        s[tid] = pairsum;
        __syncthreads();
        for (int off = 1; off < 256; off <<= 1) {
            int add = (tid >= off) ? s[tid - off] : 0;
            __syncthreads();
            s[tid] += add;
            __syncthreads();
        }
        int exc = s[tid] - pairsum;               // exclusive over pairs
        pcnt[base + 2 * tid]     = exc;
        pcnt[base + 2 * tid + 1] = exc + v0;
        if (tid == 255) tot[b] = s[255];
    }
    grid.sync();

    // ---- P3: exclusive scan of bucket totals -> bbase[0..NBK] (block 0) ----
    if (b == 0) {
        int i0 = 2 * tid, i1 = 2 * tid + 1;
        int v0 = (i0 < NBK) ? tot[i0] : 0;
        int v1 = (i1 < NBK) ? tot[i1] : 0;
        int pairsum = v0 + v1;
        s[tid] = pairsum;
        __syncthreads();
        for (int off = 1; off < 256; off <<= 1) {
            int add = (tid >= off) ? s[tid - off] : 0;
            __syncthreads();
            s[tid] += add;
            __syncthreads();
        }
        int exc = s[tid] - pairsum;
        if (i0 <= NBK) bbase[i0] = exc;           // i0==NBK impossible (NBK odd)
        if (i1 <= NBK) bbase[i1] = exc + v0;      // writes bbase[NBK]=total at i1==NBK
    }
    grid.sync();

    // ---- P4: scatter records {dl:7|src:17, ea} grouped by bucket ----
    for (int i = tid; i < NBK; i += 256)
        h[i] = bbase[i] + pcnt[(size_t)i * EBLK + b];
    __syncthreads();
    {
        int base = b * EPB;
        for (int e = base + tid; e < base + EPB; e += 256) {
            int dst = ei[NE + e];
            int src = ei[e];
            int k = dst >> 7;
            int pos = atomicAdd(&h[k], 1);
            recs[pos] = make_int2(((dst & 127) << 17) | src, __float_as_int(ea[e]));
        }
    }
    grid.sync();

    // ---- P5: per-bucket deg/indeg + in-bucket scan -> offs, dis; recs -> csr ----
    if (b < NBK) {
        int lo = b * NB;
        int nLoc = min(NB, NN - lo);
        for (int i = tid; i < nLoc; i += 256) { degs[i] = 0.f; cnts[i] = 0; }
        __syncthreads();
        int start = bbase[b], end = bbase[b + 1];
        for (int e = start + tid; e < end; e += 256) {
            int2 r = recs[e];
            int dl = r.x >> 17;
            atomicAdd(&degs[dl], __int_as_float(r.y));
            atomicAdd(&cnts[dl], 1);
        }
        __syncthreads();
        for (int i = tid; i < nLoc; i += 256) {
            float d = rsqrtf(degs[i] + 1.0f);
            wdst[i] = d;
            dis[lo + i] = d;
            indeg[lo + i] = cnts[i];
        }
        if (tid < NB) sc[tid] = (tid < nLoc) ? cnts[tid] : 0;
        __syncthreads();
        for (int off = 1; off < NB; off <<= 1) {
            int add = (tid < NB && tid >= off) ? sc[tid - off] : 0;
            __syncthreads();
            if (tid < NB) sc[tid] += add;
            __syncthreads();
        }
        if (tid < nLoc) {
            int ex = start + sc[tid] - cnts[tid];
            offs[lo + tid] = ex;
            curs[tid] = ex;
        }
        __syncthreads();
        for (int e = start + tid; e < end; e += 256) {
            int2 r = recs[e];
            int src = r.x & 0x1FFFF;
            int dl = r.x >> 17;
            float pw = __int_as_float(r.y) * wdst[dl];   // ea * dis[dst]
            int pos = atomicAdd(&curs[dl], 1);
            csr[pos] = make_int2(src, __float_as_int(pw));
        }
    }
}

// ---- tiled GEMM: 64 rows x 64 cols per block, X transposed in LDS ----
// Yb[n,HID] = bf16( dis[n] * (X[n,K] @ W[K,HID]) ).  4x4 register tile/thread.
template <int K>
__global__ __launch_bounds__(256) void gemm_kernel(const float* __restrict__ X,
                                                   const float* __restrict__ W,
                                                   const float* __restrict__ dis,
                                                   ushort_t* __restrict__ Yb) {
    __shared__ float w_lds[K * HID];     // [K][64]
    __shared__ float x_lds[K][65];       // transposed [k][row], pad 65
    int tid = threadIdx.x;
    int rowbase = blockIdx.x * 64;
    for (int i = tid; i < K * HID; i += 256) w_lds[i] = W[i];
    for (int i = tid; i < 16 * K; i += 256) {
        int row = i / (K / 4);
        int k4 = i % (K / 4);
        int r = rowbase + row;
        float4 v = (r < NN) ? ((const float4*)(X + (size_t)r * K))[k4]
                            : make_float4(0.f, 0.f, 0.f, 0.f);
        x_lds[k4 * 4 + 0][row] = v.x;
        x_lds[k4 * 4 + 1][row] = v.y;
        x_lds[k4 * 4 + 2][row] = v.z;
        x_lds[k4 * 4 + 3][row] = v.w;
    }
    __syncthreads();
    int c0 = (tid & 15) * 4;
    int r0 = (tid >> 4) * 4;
    float acc[4][4] = {};
#pragma unroll 4
    for (int k = 0; k < K; ++k) {
        float x0 = x_lds[k][r0 + 0];
        float x1 = x_lds[k][r0 + 1];
        float x2 = x_lds[k][r0 + 2];
        float x3 = x_lds[k][r0 + 3];
        float4 wv = *(const float4*)&w_lds[k * HID + c0];
        acc[0][0] += x0 * wv.x; acc[0][1] += x0 * wv.y; acc[0][2] += x0 * wv.z; acc[0][3] += x0 * wv.w;
        acc[1][0] += x1 * wv.x; acc[1][1] += x1 * wv.y; acc[1][2] += x1 * wv.z; acc[1][3] += x1 * wv.w;
        acc[2][0] += x2 * wv.x; acc[2][1] += x2 * wv.y; acc[2][2] += x2 * wv.z; acc[2][3] += x2 * wv.w;
        acc[3][0] += x3 * wv.x; acc[3][1] += x3 * wv.y; acc[3][2] += x3 * wv.z; acc[3][3] += x3 * wv.w;
    }
#pragma unroll
    for (int i = 0; i < 4; ++i) {
        int r = rowbase + r0 + i;
        if (r < NN) {
            float dr = dis[r];
            ushort4 o;
            o.x = f2bf(dr * acc[i][0]); o.y = f2bf(dr * acc[i][1]);
            o.z = f2bf(dr * acc[i][2]); o.w = f2bf(dr * acc[i][3]);
            *(ushort4*)&Yb[(size_t)r * HID + c0] = o;
        }
    }
}

// ---- gather1: h1[node] = relu( agg(A1) + dis*A1[node] + b1 )  (fp32 out) ----
__global__ void gather1_kernel(const int2* __restrict__ csr,
                               const int* __restrict__ offs,
                               const int* __restrict__ indeg,
                               const float* __restrict__ dis,
                               const ushort_t* __restrict__ A1,
                               const float* __restrict__ b1,
                               float* __restrict__ OUT) {
    int node = blockIdx.x * 4 + (threadIdx.x >> 6);
    int lane = threadIdx.x & 63;
    if (node >= NN) return;
    int o  = lane >> 3;
    int cl = lane & 7;
    int start = offs[node];
    int n = indeg[node];
    float a0 = 0.f, a1 = 0.f, a2 = 0.f, a3 = 0.f;
    float a4 = 0.f, a5 = 0.f, a6 = 0.f, a7 = 0.f;
    for (int c = 0; c < n; c += 64) {
        int idx = c + lane;
        int2 rec = (idx < n) ? csr[start + idx] : make_int2(0, 0);  // w=0 pad
        int tmax = min(n - c, 64);
#pragma unroll 2
        for (int t = 0; t * 8 < tmax; ++t) {
            int sl = t * 8 + o;
            int key = __shfl(rec.x, sl, 64);
            float w = __int_as_float(__shfl(rec.y, sl, 64));
            uint4 v = *(const uint4*)(A1 + ((size_t)key << 6) + (cl << 3));
            a0 += w * bflo(v.x); a1 += w * bfhi(v.x);
            a2 += w * bflo(v.y); a3 += w * bfhi(v.y);
            a4 += w * bflo(v.z); a5 += w * bfhi(v.z);
            a6 += w * bflo(v.w); a7 += w * bfhi(v.w);
        }
    }
    a0 += __shfl_xor(a0, 8, 64); a0 += __shfl_xor(a0, 16, 64); a0 += __shfl_xor(a0, 32, 64);
    a1 += __shfl_xor(a1, 8, 64); a1 += __shfl_xor(a1, 16, 64); a1 += __shfl_xor(a1, 32, 64);
    a2 += __shfl_xor(a2, 8, 64); a2 += __shfl_xor(a2, 16, 64); a2 += __shfl_xor(a2, 32, 64);
    a3 += __shfl_xor(a3, 8, 64); a3 += __shfl_xor(a3, 16, 64); a3 += __shfl_xor(a3, 32, 64);
    a4 += __shfl_xor(a4, 8, 64); a4 += __shfl_xor(a4, 16, 64); a4 += __shfl_xor(a4, 32, 64);
    a5 += __shfl_xor(a5, 8, 64); a5 += __shfl_xor(a5, 16, 64); a5 += __shfl_xor(a5, 32, 64);
    a6 += __shfl_xor(a6, 8, 64); a6 += __shfl_xor(a6, 16, 64); a6 += __shfl_xor(a6, 32, 64);
    a7 += __shfl_xor(a7, 8, 64); a7 += __shfl_xor(a7, 16, 64); a7 += __shfl_xor(a7, 32, 64);
    if (o == 0) {
        float d = dis[node];
        uint4 sv = *(const uint4*)(A1 + ((size_t)node << 6) + (cl << 3));
        const float4* bv = (const float4*)(b1 + (cl << 3));
        float4 bA = bv[0], bB = bv[1];
        float o0 = fmaxf(a0 + d * bflo(sv.x) + bA.x, 0.f);
        float o1 = fmaxf(a1 + d * bfhi(sv.x) + bA.y, 0.f);
        float o2 = fmaxf(a2 + d * bflo(sv.y) + bA.z, 0.f);
        float o3 = fmaxf(a3 + d * bfhi(sv.y) + bA.w, 0.f);
        float o4 = fmaxf(a4 + d * bflo(sv.z) + bB.x, 0.f);
        float o5 = fmaxf(a5 + d * bfhi(sv.z) + bB.y, 0.f);
        float o6 = fmaxf(a6 + d * bflo(sv.w) + bB.z, 0.f);
        float o7 = fmaxf(a7 + d * bfhi(sv.w) + bB.w, 0.f);
        float* op = &OUT[((size_t)node << 6) + (cl << 3)];
        *(float4*)op       = make_float4(o0, o1, o2, o3);
        *(float4*)(op + 4) = make_float4(o4, o5, o6, o7);
    }
}

// ---- gather2 + fused head: nodeval[node] = dot(agg(A2)+self+b2, Wlin) ----
__global__ void gather2_kernel(const int2* __restrict__ csr,
                               const int* __restrict__ offs,
                               const int* __restrict__ indeg,
                               const float* __restrict__ dis,
                               const ushort_t* __restrict__ A2,
                               const float* __restrict__ b2,
                               const float* __restrict__ Wlin,
                               float* __restrict__ nodeval) {
    int node = blockIdx.x * 4 + (threadIdx.x >> 6);
    int lane = threadIdx.x & 63;
    if (node >= NN) return;
    int o  = lane >> 3;
    int cl = lane & 7;
    int start = offs[node];
    int n = indeg[node];
    float a0 = 0.f, a1 = 0.f, a2 = 0.f, a3 = 0.f;
    float a4 = 0.f, a5 = 0.f, a6 = 0.f, a7 = 0.f;
    for (int c = 0; c < n; c += 64) {
        int idx = c + lane;
        int2 rec = (idx < n) ? csr[start + idx] : make_int2(0, 0);
        int tmax = min(n - c, 64);
#pragma unroll 2
        for (int t = 0; t * 8 < tmax; ++t) {
            int sl = t * 8 + o;
            int key = __shfl(rec.x, sl, 64);
            float w = __int_as_float(__shfl(rec.y, sl, 64));
            uint4 v = *(const uint4*)(A2 + ((size_t)key << 6) + (cl << 3));
            a0 += w * bflo(v.x); a1 += w * bfhi(v.x);
            a2 += w * bflo(v.y); a3 += w * bfhi(v.y);
            a4 += w * bflo(v.z); a5 += w * bfhi(v.z);
            a6 += w * bflo(v.w); a7 += w * bfhi(v.w);
        }
    }
    a0 += __shfl_xor(a0, 8, 64); a0 += __shfl_xor(a0, 16, 64); a0 += __shfl_xor(a0, 32, 64);
    a1 += __shfl_xor(a1, 8, 64); a1 += __shfl_xor(a1, 16, 64); a1 += __shfl_xor(a1, 32, 64);
    a2 += __shfl_xor(a2, 8, 64); a2 += __shfl_xor(a2, 16, 64); a2 += __shfl_xor(a2, 32, 64);
    a3 += __shfl_xor(a3, 8, 64); a3 += __shfl_xor(a3, 16, 64); a3 += __shfl_xor(a3, 32, 64);
    a4 += __shfl_xor(a4, 8, 64); a4 += __shfl_xor(a4, 16, 64); a4 += __shfl_xor(a4, 32, 64);
    a5 += __shfl_xor(a5, 8, 64); a5 += __shfl_xor(a5, 16, 64); a5 += __shfl_xor(a5, 32, 64);
    a6 += __shfl_xor(a6, 8, 64); a6 += __shfl_xor(a6, 16, 64); a6 += __shfl_xor(a6, 32, 64);
    a7 += __shfl_xor(a7, 8, 64); a7 += __shfl_xor(a7, 16, 64); a7 += __shfl_xor(a7, 32, 64);
    float d = dis[node];
    uint4 sv = *(const uint4*)(A2 + ((size_t)node << 6) + (cl << 3));
    const float4* bv = (const float4*)(b2 + (cl << 3));
    float4 bA = bv[0], bB = bv[1];
    const float4* wv = (const float4*)(Wlin + (cl << 3));
    float4 wA = wv[0], wB = wv[1];
    float dot = (a0 + d * bflo(sv.x) + bA.x) * wA.x
              + (a1 + d * bfhi(sv.x) + bA.y) * wA.y
              + (a2 + d * bflo(sv.y) + bA.z) * wA.z
              + (a3 + d * bfhi(sv.y) + bA.w) * wA.w
              + (a4 + d * bflo(sv.z) + bB.x) * wB.x
              + (a5 + d * bfhi(sv.z) + bB.y) * wB.y
              + (a6 + d * bflo(sv.w) + bB.z) * wB.z
              + (a7 + d * bfhi(sv.w) + bB.w) * wB.w;
    dot += __shfl_xor(dot, 1, 64);
    dot += __shfl_xor(dot, 2, 64);
    dot += __shfl_xor(dot, 4, 64);
    if (lane == 0) nodeval[node] = dot;
}

// out[g] = (sum of nodeval in batch range g)/cnt + blin   (1 block/graph)
__global__ void pool_final_kernel(const float* __restrict__ nodeval,
                                  const int* __restrict__ batch,
                                  const float* __restrict__ blin,
                                  float* __restrict__ out) {
    __shared__ int bnd[2];
    __shared__ float red[4];
    int g = blockIdx.x;
    if (threadIdx.x < 2) {
        int target = g + threadIdx.x;
        int lo = 0, hi = NN;
        while (lo < hi) {
            int mid = (lo + hi) >> 1;
            if (batch[mid] < target) lo = mid + 1; else hi = mid;
        }
        bnd[threadIdx.x] = lo;
    }
    __syncthreads();
    int s = bnd[0], e = bnd[1];
    float a = 0.f;
    for (int i = s + threadIdx.x; i < e; i += 256) a += nodeval[i];
    for (int off = 32; off > 0; off >>= 1) a += __shfl_down(a, off, 64);
    int lane = threadIdx.x & 63;
    int wv = threadIdx.x >> 6;
    if (lane == 0) red[wv] = a;
    __syncthreads();
    if (threadIdx.x == 0) {
        float t = red[0] + red[1] + red[2] + red[3];
        out[g] = t / fmaxf((float)(e - s), 1.0f) + blin[0];
    }
}

extern "C" void kernel_launch(void* const* d_in, const int* in_sizes, int n_in,
                              void* d_out, int out_size, void* d_ws, size_t ws_size,
                              hipStream_t stream) {
    const float* x     = (const float*)d_in[0];
    const int*   ei    = (const int*)d_in[1];
    const float* ea    = (const float*)d_in[2];
    const int*   batch = (const int*)d_in[3];
    const float* W1    = (const float*)d_in[4];
    const float* b1    = (const float*)d_in[5];
    const float* W2    = (const float*)d_in[6];
    const float* b2    = (const float*)d_in[7];
    const float* Wlin  = (const float*)d_in[8];
    const float* blin  = (const float*)d_in[9];
    float*       out   = (float*)d_out;

    char* ws = (char*)d_ws;
    auto alloc = [&](size_t bytes) {
        void* p = (void*)ws;
        ws += (bytes + 255) / 256 * 256;
        return p;
    };
    float*    dis     = (float*)alloc((size_t)NN * 4);
    int*      indeg   = (int*)alloc((size_t)NN * 4);
    int*      offs    = (int*)alloc((size_t)NN * 4);
    int*      pcnt    = (int*)alloc((size_t)NBK * EBLK * 4);
    int*      tot     = (int*)alloc((size_t)NBK * 4);
    int*      bbase   = (int*)alloc((size_t)(NBK + 1) * 4);
    int2*     recs    = (int2*)alloc((size_t)NE * 8);   // dead after build -> A1|A2
    int2*     csr     = (int2*)alloc((size_t)NE * 8);   // {src, ea*dis[dst]}
    float*    B       = (float*)alloc((size_t)NN * HID * 4);  // fp32 h1
    float*    nodeval = (float*)alloc((size_t)NN * 4);
    ushort_t* A1      = (ushort_t*)recs;                      // bf16 dis*(x@W1)
    ushort_t* A2      = (ushort_t*)recs + (size_t)NN * HID;   // bf16 dis*(h1@W2)

    // fused build (cooperative: 5 phases with grid syncs)
    {
        void* args[] = {(void*)&ei, (void*)&ea, (void*)&pcnt, (void*)&tot,
                        (void*)&bbase, (void*)&indeg, (void*)&dis, (void*)&offs,
                        (void*)&recs, (void*)&csr};
        hipLaunchCooperativeKernel((void*)build_kernel, dim3(EBLK), dim3(256),
                                   args, 0, stream);
    }

    // conv1: A1 = bf16(dis*(x@W1));  h1 = relu(agg(A1)+self+b1)  (fp32)
    gemm_kernel<IN_DIM><<<(NN + 63) / 64, 256, 0, stream>>>(x, W1, dis, A1);
    gather1_kernel<<<(NN + 3) / 4, 256, 0, stream>>>(csr, offs, indeg, dis, A1, b1, B);

    // conv2: A2 = bf16(dis*(h1@W2));  gather2 + head -> nodeval
    gemm_kernel<HID><<<(NN + 63) / 64, 256, 0, stream>>>(B, W2, dis, A2);
    gather2_kernel<<<(NN + 3) / 4, 256, 0, stream>>>(csr, offs, indeg, dis, A2, b2,
                                                     Wlin, nodeval);

    // segmented mean + blin
    pool_final_kernel<<<NG, 256, 0, stream>>>(nodeval, batch, blin, out);
}

// Round 17
// 165.783 us; speedup vs baseline: 2.4177x; 2.4177x over previous
//
#include <hip/hip_runtime.h>

#define NN 50000
#define NE 1600000
#define NG 512
#define IN_DIM 128
#define HID 64

#define NB 128                       // nodes per bucket
#define NBK ((NN + NB - 1) / NB)     // 391 buckets
#define EBLK 256                     // edge-pass blocks
#define EPB (NE / EBLK)              // 6250 edges per block

typedef unsigned short ushort_t;
typedef unsigned int uint_t;

// float -> bf16 (RNE)
static __device__ __forceinline__ ushort_t f2bf(float f) {
    uint_t u = __float_as_uint(f);
    u += 0x7FFFu + ((u >> 16) & 1u);
    return (ushort_t)(u >> 16);
}
static __device__ __forceinline__ float bflo(uint_t u) { return __uint_as_float(u << 16); }
static __device__ __forceinline__ float bfhi(uint_t u) { return __uint_as_float(u & 0xFFFF0000u); }

// ---- pass 1: per-block coarse histogram of dst>>7 ----
__global__ void cnt_kernel(const int* __restrict__ ei, int* __restrict__ pcnt) {
    __shared__ int h[NBK];
    for (int i = threadIdx.x; i < NBK; i += blockDim.x) h[i] = 0;
    __syncthreads();
    int base = blockIdx.x * EPB;
    for (int e = base + threadIdx.x; e < base + EPB; e += blockDim.x)
        atomicAdd(&h[ei[NE + e] >> 7], 1);
    __syncthreads();
    for (int i = threadIdx.x; i < NBK; i += blockDim.x)
        pcnt[(size_t)i * EBLK + blockIdx.x] = h[i];
}

// ---- pass 2a: per-bucket exclusive scan over the EBLK partials ----
__global__ void bscan_kernel(int* __restrict__ pcnt, int* __restrict__ tot) {
    __shared__ int s[EBLK];
    int k = blockIdx.x, t = threadIdx.x;
    int v = pcnt[(size_t)k * EBLK + t];
    s[t] = v;
    __syncthreads();
    for (int off = 1; off < EBLK; off <<= 1) {
        int add = (t >= off) ? s[t - off] : 0;
        __syncthreads();
        s[t] += add;
        __syncthreads();
    }
    pcnt[(size_t)k * EBLK + t] = s[t] - v;   // exclusive within bucket
    if (t == EBLK - 1) tot[k] = s[t];
}

// ---- pass 2b: exclusive scan of bucket totals -> bbase[0..NBK] ----
__global__ void tscan_kernel(const int* __restrict__ tot, int* __restrict__ bbase) {
    __shared__ int s[512];
    int t = threadIdx.x;
    int v = (t < NBK) ? tot[t] : 0;
    s[t] = v;
    __syncthreads();
    for (int off = 1; off < 512; off <<= 1) {
        int add = (t >= off) ? s[t - off] : 0;
        __syncthreads();
        s[t] += add;
        __syncthreads();
    }
    if (t < NBK) bbase[t] = s[t] - v;
    if (t == NBK - 1) bbase[NBK] = s[t];
}

// ---- pass 3: scatter records {dl:7|src:17, ea} grouped by bucket ----
__global__ void scatter_kernel(const int* __restrict__ ei, const float* __restrict__ ea,
                               const int* __restrict__ pcnt, const int* __restrict__ bbase,
                               int2* __restrict__ recs) {
    __shared__ int curs[NBK];
    int b = blockIdx.x;
    for (int i = threadIdx.x; i < NBK; i += blockDim.x)
        curs[i] = bbase[i] + pcnt[(size_t)i * EBLK + b];
    __syncthreads();
    int base = b * EPB;
    for (int e = base + threadIdx.x; e < base + EPB; e += blockDim.x) {
        int dst = ei[NE + e];
        int src = ei[e];
        int k = dst >> 7;
        int pos = atomicAdd(&curs[k], 1);
        recs[pos] = make_int2(((dst & 127) << 17) | src, __float_as_int(ea[e]));
    }
}

// ---- merged bucket pass: deg/indeg + in-bucket scan -> offs, dis; then
//      scatter bucket recs to exact per-node CSR {src, ea*dis[dst]} ----
__global__ void binfo2_kernel(const int2* __restrict__ recs, const int* __restrict__ bbase,
                              int* __restrict__ indeg, float* __restrict__ dis,
                              int* __restrict__ offs, int2* __restrict__ csr) {
    __shared__ float deg[NB];
    __shared__ int cnt[NB];
    __shared__ int sc[NB];
    __shared__ int curs[NB];
    __shared__ float wdst[NB];
    int k = blockIdx.x;
    int lo = k * NB;
    int nLoc = min(NB, NN - lo);
    int tid = threadIdx.x;
    for (int i = tid; i < nLoc; i += blockDim.x) { deg[i] = 0.f; cnt[i] = 0; }
    __syncthreads();
    int start = bbase[k], end = bbase[k + 1];
    for (int e = start + tid; e < end; e += blockDim.x) {
        int2 r = recs[e];
        int dl = r.x >> 17;
        atomicAdd(&deg[dl], __int_as_float(r.y));
        atomicAdd(&cnt[dl], 1);
    }
    __syncthreads();
    for (int i = tid; i < nLoc; i += blockDim.x) {
        float d = rsqrtf(deg[i] + 1.0f);
        wdst[i] = d;
        dis[lo + i] = d;
        indeg[lo + i] = cnt[i];
    }
    if (tid < NB) sc[tid] = (tid < nLoc) ? cnt[tid] : 0;
    __syncthreads();
    // inclusive scan over 128 bins
    for (int off = 1; off < NB; off <<= 1) {
        int add = (tid < NB && tid >= off) ? sc[tid - off] : 0;
        __syncthreads();
        if (tid < NB) sc[tid] += add;
        __syncthreads();
    }
    if (tid < nLoc) {
        int ex = start + sc[tid] - cnt[tid];   // exclusive position
        offs[lo + tid] = ex;
        curs[tid] = ex;
    }
    __syncthreads();
    for (int e = start + tid; e < end; e += blockDim.x) {
        int2 r = recs[e];
        int src = r.x & 0x1FFFF;
        int dl = r.x >> 17;
        float pw = __int_as_float(r.y) * wdst[dl];   // ea * dis[dst]
        int pos = atomicAdd(&curs[dl], 1);
        csr[pos] = make_int2(src, __float_as_int(pw));
    }
}

// ---- tiled GEMM: 64 rows x 64 cols per block, X transposed in LDS ----
// Yb[n,HID] = bf16( dis[n] * (X[n,K] @ W[K,HID]) ).  4x4 register tile/thread.
template <int K>
__global__ __launch_bounds__(256) void gemm_kernel(const float* __restrict__ X,
                                                   const float* __restrict__ W,
                                                   const float* __restrict__ dis,
                                                   ushort_t* __restrict__ Yb) {
    __shared__ float w_lds[K * HID];     // [K][64]
    __shared__ float x_lds[K][65];       // transposed [k][row], pad 65
    int tid = threadIdx.x;
    int rowbase = blockIdx.x * 64;
    for (int i = tid; i < K * HID; i += 256) w_lds[i] = W[i];
    for (int i = tid; i < 16 * K; i += 256) {
        int row = i / (K / 4);
        int k4 = i % (K / 4);
        int r = rowbase + row;
        float4 v = (r < NN) ? ((const float4*)(X + (size_t)r * K))[k4]
                            : make_float4(0.f, 0.f, 0.f, 0.f);
        x_lds[k4 * 4 + 0][row] = v.x;
        x_lds[k4 * 4 + 1][row] = v.y;
        x_lds[k4 * 4 + 2][row] = v.z;
        x_lds[k4 * 4 + 3][row] = v.w;
    }
    __syncthreads();
    int c0 = (tid & 15) * 4;
    int r0 = (tid >> 4) * 4;
    float acc[4][4] = {};
#pragma unroll 4
    for (int k = 0; k < K; ++k) {
        float x0 = x_lds[k][r0 + 0];
        float x1 = x_lds[k][r0 + 1];
        float x2 = x_lds[k][r0 + 2];
        float x3 = x_lds[k][r0 + 3];
        float4 wv = *(const float4*)&w_lds[k * HID + c0];
        acc[0][0] += x0 * wv.x; acc[0][1] += x0 * wv.y; acc[0][2] += x0 * wv.z; acc[0][3] += x0 * wv.w;
        acc[1][0] += x1 * wv.x; acc[1][1] += x1 * wv.y; acc[1][2] += x1 * wv.z; acc[1][3] += x1 * wv.w;
        acc[2][0] += x2 * wv.x; acc[2][1] += x2 * wv.y; acc[2][2] += x2 * wv.z; acc[2][3] += x2 * wv.w;
        acc[3][0] += x3 * wv.x; acc[3][1] += x3 * wv.y; acc[3][2] += x3 * wv.z; acc[3][3] += x3 * wv.w;
    }
#pragma unroll
    for (int i = 0; i < 4; ++i) {
        int r = rowbase + r0 + i;
        if (r < NN) {
            float dr = dis[r];
            ushort4 o;
            o.x = f2bf(dr * acc[i][0]); o.y = f2bf(dr * acc[i][1]);
            o.z = f2bf(dr * acc[i][2]); o.w = f2bf(dr * acc[i][3]);
            *(ushort4*)&Yb[(size_t)r * HID + c0] = o;
        }
    }
}

// ---- gather1: h1[node] = relu( agg(A1) + dis*A1[node] + b1 )  (fp32 out) ----
__global__ void gather1_kernel(const int2* __restrict__ csr,
                               const int* __restrict__ offs,
                               const int* __restrict__ indeg,
                               const float* __restrict__ dis,
                               const ushort_t* __restrict__ A1,
                               const float* __restrict__ b1,
                               float* __restrict__ OUT) {
    int node = blockIdx.x * 4 + (threadIdx.x >> 6);
    int lane = threadIdx.x & 63;
    if (node >= NN) return;
    int o  = lane >> 3;
    int cl = lane & 7;
    int start = offs[node];
    int n = indeg[node];
    float a0 = 0.f, a1 = 0.f, a2 = 0.f, a3 = 0.f;
    float a4 = 0.f, a5 = 0.f, a6 = 0.f, a7 = 0.f;
    for (int c = 0; c < n; c += 64) {
        int idx = c + lane;
        int2 rec = (idx < n) ? csr[start + idx] : make_int2(0, 0);  // w=0 pad
        int tmax = min(n - c, 64);
#pragma unroll 2
        for (int t = 0; t * 8 < tmax; ++t) {
            int sl = t * 8 + o;
            int key = __shfl(rec.x, sl, 64);
            float w = __int_as_float(__shfl(rec.y, sl, 64));
            uint4 v = *(const uint4*)(A1 + ((size_t)key << 6) + (cl << 3));
            a0 += w * bflo(v.x); a1 += w * bfhi(v.x);
            a2 += w * bflo(v.y); a3 += w * bfhi(v.y);
            a4 += w * bflo(v.z); a5 += w * bfhi(v.z);
            a6 += w * bflo(v.w); a7 += w * bfhi(v.w);
        }
    }
    a0 += __shfl_xor(a0, 8, 64); a0 += __shfl_xor(a0, 16, 64); a0 += __shfl_xor(a0, 32, 64);
    a1 += __shfl_xor(a1, 8, 64); a1 += __shfl_xor(a1, 16, 64); a1 += __shfl_xor(a1, 32, 64);
    a2 += __shfl_xor(a2, 8, 64); a2 += __shfl_xor(a2, 16, 64); a2 += __shfl_xor(a2, 32, 64);
    a3 += __shfl_xor(a3, 8, 64); a3 += __shfl_xor(a3, 16, 64); a3 += __shfl_xor(a3, 32, 64);
    a4 += __shfl_xor(a4, 8, 64); a4 += __shfl_xor(a4, 16, 64); a4 += __shfl_xor(a4, 32, 64);
    a5 += __shfl_xor(a5, 8, 64); a5 += __shfl_xor(a5, 16, 64); a5 += __shfl_xor(a5, 32, 64);
    a6 += __shfl_xor(a6, 8, 64); a6 += __shfl_xor(a6, 16, 64); a6 += __shfl_xor(a6, 32, 64);
    a7 += __shfl_xor(a7, 8, 64); a7 += __shfl_xor(a7, 16, 64); a7 += __shfl_xor(a7, 32, 64);
    if (o == 0) {
        float d = dis[node];
        uint4 sv = *(const uint4*)(A1 + ((size_t)node << 6) + (cl << 3));
        const float4* bv = (const float4*)(b1 + (cl << 3));
        float4 bA = bv[0], bB = bv[1];
        float o0 = fmaxf(a0 + d * bflo(sv.x) + bA.x, 0.f);
        float o1 = fmaxf(a1 + d * bfhi(sv.x) + bA.y, 0.f);
        float o2 = fmaxf(a2 + d * bflo(sv.y) + bA.z, 0.f);
        float o3 = fmaxf(a3 + d * bfhi(sv.y) + bA.w, 0.f);
        float o4 = fmaxf(a4 + d * bflo(sv.z) + bB.x, 0.f);
        float o5 = fmaxf(a5 + d * bfhi(sv.z) + bB.y, 0.f);
        float o6 = fmaxf(a6 + d * bflo(sv.w) + bB.z, 0.f);
        float o7 = fmaxf(a7 + d * bfhi(sv.w) + bB.w, 0.f);
        float* op = &OUT[((size_t)node << 6) + (cl << 3)];
        *(float4*)op       = make_float4(o0, o1, o2, o3);
        *(float4*)(op + 4) = make_float4(o4, o5, o6, o7);
    }
}

// ---- gather2 + fused head: nodeval[node] = dot(agg(A2)+self+b2, Wlin) ----
__global__ void gather2_kernel(const int2* __restrict__ csr,
                               const int* __restrict__ offs,
                               const int* __restrict__ indeg,
                               const float* __restrict__ dis,
                               const ushort_t* __restrict__ A2,
                               const float* __restrict__ b2,
                               const float* __restrict__ Wlin,
                               float* __restrict__ nodeval) {
    int node = blockIdx.x * 4 + (threadIdx.x >> 6);
    int lane = threadIdx.x & 63;
    if (node >= NN) return;
    int o  = lane >> 3;
    int cl = lane & 7;
    int start = offs[node];
    int n = indeg[node];
    float a0 = 0.f, a1 = 0.f, a2 = 0.f, a3 = 0.f;
    float a4 = 0.f, a5 = 0.f, a6 = 0.f, a7 = 0.f;
    for (int c = 0; c < n; c += 64) {
        int idx = c + lane;
        int2 rec = (idx < n) ? csr[start + idx] : make_int2(0, 0);
        int tmax = min(n - c, 64);
#pragma unroll 2
        for (int t = 0; t * 8 < tmax; ++t) {
            int sl = t * 8 + o;
            int key = __shfl(rec.x, sl, 64);
            float w = __int_as_float(__shfl(rec.y, sl, 64));
            uint4 v = *(const uint4*)(A2 + ((size_t)key << 6) + (cl << 3));
            a0 += w * bflo(v.x); a1 += w * bfhi(v.x);
            a2 += w * bflo(v.y); a3 += w * bfhi(v.y);
            a4 += w * bflo(v.z); a5 += w * bfhi(v.z);
            a6 += w * bflo(v.w); a7 += w * bfhi(v.w);
        }
    }
    a0 += __shfl_xor(a0, 8, 64); a0 += __shfl_xor(a0, 16, 64); a0 += __shfl_xor(a0, 32, 64);
    a1 += __shfl_xor(a1, 8, 64); a1 += __shfl_xor(a1, 16, 64); a1 += __shfl_xor(a1, 32, 64);
    a2 += __shfl_xor(a2, 8, 64); a2 += __shfl_xor(a2, 16, 64); a2 += __shfl_xor(a2, 32, 64);
    a3 += __shfl_xor(a3, 8, 64); a3 += __shfl_xor(a3, 16, 64); a3 += __shfl_xor(a3, 32, 64);
    a4 += __shfl_xor(a4, 8, 64); a4 += __shfl_xor(a4, 16, 64); a4 += __shfl_xor(a4, 32, 64);
    a5 += __shfl_xor(a5, 8, 64); a5 += __shfl_xor(a5, 16, 64); a5 += __shfl_xor(a5, 32, 64);
    a6 += __shfl_xor(a6, 8, 64); a6 += __shfl_xor(a6, 16, 64); a6 += __shfl_xor(a6, 32, 64);
    a7 += __shfl_xor(a7, 8, 64); a7 += __shfl_xor(a7, 16, 64); a7 += __shfl_xor(a7, 32, 64);
    float d = dis[node];
    uint4 sv = *(const uint4*)(A2 + ((size_t)node << 6) + (cl << 3));
    const float4* bv = (const float4*)(b2 + (cl << 3));
    float4 bA = bv[0], bB = bv[1];
    const float4* wv = (const float4*)(Wlin + (cl << 3));
    float4 wA = wv[0], wB = wv[1];
    float dot = (a0 + d * bflo(sv.x) + bA.x) * wA.x
              + (a1 + d * bfhi(sv.x) + bA.y) * wA.y
              + (a2 + d * bflo(sv.y) + bA.z) * wA.z
              + (a3 + d * bfhi(sv.y) + bA.w) * wA.w
              + (a4 + d * bflo(sv.z) + bB.x) * wB.x
              + (a5 + d * bfhi(sv.z) + bB.y) * wB.y
              + (a6 + d * bflo(sv.w) + bB.z) * wB.z
              + (a7 + d * bfhi(sv.w) + bB.w) * wB.w;
    dot += __shfl_xor(dot, 1, 64);
    dot += __shfl_xor(dot, 2, 64);
    dot += __shfl_xor(dot, 4, 64);
    if (lane == 0) nodeval[node] = dot;
}

// out[g] = (sum of nodeval in batch range g)/cnt + blin   (1 block/graph)
__global__ void pool_final_kernel(const float* __restrict__ nodeval,
                                  const int* __restrict__ batch,
                                  const float* __restrict__ blin,
                                  float* __restrict__ out) {
    __shared__ int bnd[2];
    __shared__ float red[4];
    int g = blockIdx.x;
    if (threadIdx.x < 2) {
        int target = g + threadIdx.x;
        int lo = 0, hi = NN;
        while (lo < hi) {
            int mid = (lo + hi) >> 1;
            if (batch[mid] < target) lo = mid + 1; else hi = mid;
        }
        bnd[threadIdx.x] = lo;
    }
    __syncthreads();
    int s = bnd[0], e = bnd[1];
    float a = 0.f;
    for (int i = s + threadIdx.x; i < e; i += 256) a += nodeval[i];
    for (int off = 32; off > 0; off >>= 1) a += __shfl_down(a, off, 64);
    int lane = threadIdx.x & 63;
    int wv = threadIdx.x >> 6;
    if (lane == 0) red[wv] = a;
    __syncthreads();
    if (threadIdx.x == 0) {
        float t = red[0] + red[1] + red[2] + red[3];
        out[g] = t / fmaxf((float)(e - s), 1.0f) + blin[0];
    }
}

extern "C" void kernel_launch(void* const* d_in, const int* in_sizes, int n_in,
                              void* d_out, int out_size, void* d_ws, size_t ws_size,
                              hipStream_t stream) {
    const float* x     = (const float*)d_in[0];
    const int*   ei    = (const int*)d_in[1];
    const float* ea    = (const float*)d_in[2];
    const int*   batch = (const int*)d_in[3];
    const float* W1    = (const float*)d_in[4];
    const float* b1    = (const float*)d_in[5];
    const float* W2    = (const float*)d_in[6];
    const float* b2    = (const float*)d_in[7];
    const float* Wlin  = (const float*)d_in[8];
    const float* blin  = (const float*)d_in[9];
    float*       out   = (float*)d_out;

    char* ws = (char*)d_ws;
    auto alloc = [&](size_t bytes) {
        void* p = (void*)ws;
        ws += (bytes + 255) / 256 * 256;
        return p;
    };
    float*    dis     = (float*)alloc((size_t)NN * 4);
    int*      indeg   = (int*)alloc((size_t)NN * 4);
    int*      offs    = (int*)alloc((size_t)NN * 4);
    int*      pcnt    = (int*)alloc((size_t)NBK * EBLK * 4);
    int*      tot     = (int*)alloc((size_t)NBK * 4);
    int*      bbase   = (int*)alloc((size_t)(NBK + 1) * 4);
    int2*     recs    = (int2*)alloc((size_t)NE * 8);   // dead after binfo2 -> A1|A2
    int2*     csr     = (int2*)alloc((size_t)NE * 8);   // {src, ea*dis[dst]}
    float*    B       = (float*)alloc((size_t)NN * HID * 4);  // fp32 h1
    float*    nodeval = (float*)alloc((size_t)NN * 4);
    ushort_t* A1      = (ushort_t*)recs;                      // bf16 dis*(x@W1)
    ushort_t* A2      = (ushort_t*)recs + (size_t)NN * HID;   // bf16 dis*(h1@W2)

    // two-level bucket sort of edges by dst (no global atomics)
    cnt_kernel<<<EBLK, 256, 0, stream>>>(ei, pcnt);
    bscan_kernel<<<NBK, EBLK, 0, stream>>>(pcnt, tot);
    tscan_kernel<<<1, 512, 0, stream>>>(tot, bbase);
    scatter_kernel<<<EBLK, 256, 0, stream>>>(ei, ea, pcnt, bbase, recs);
    binfo2_kernel<<<NBK, 256, 0, stream>>>(recs, bbase, indeg, dis, offs, csr);

    // conv1: A1 = bf16(dis*(x@W1));  h1 = relu(agg(A1)+self+b1)  (fp32)
    gemm_kernel<IN_DIM><<<(NN + 63) / 64, 256, 0, stream>>>(x, W1, dis, A1);
    gather1_kernel<<<(NN + 3) / 4, 256, 0, stream>>>(csr, offs, indeg, dis, A1, b1, B);

    // conv2: A2 = bf16(dis*(h1@W2));  gather2 + head -> nodeval
    gemm_kernel<HID><<<(NN + 63) / 64, 256, 0, stream>>>(B, W2, dis, A2);
    gather2_kernel<<<(NN + 3) / 4, 256, 0, stream>>>(csr, offs, indeg, dis, A2, b2,
                                                     Wlin, nodeval);

    // segmented mean + blin
    pool_final_kernel<<<NG, 256, 0, stream>>>(nodeval, batch, blin, out);
}

// Round 18
// 153.727 us; speedup vs baseline: 2.6073x; 1.0784x over previous
//
#include <hip/hip_runtime.h>

#define NN 50000
#define NE 1600000
#define NG 512
#define IN_DIM 128
#define HID 64

#define NB 128                       // nodes per bucket
#define NBK ((NN + NB - 1) / NB)     // 391 buckets
#define EBLK 250                     // edge-pass blocks
#define EPB (NE / EBLK)              // 6400 edges per block (div by 4)
#define EPB4 (EPB / 4)               // 1600 int4 groups

typedef unsigned short ushort_t;
typedef unsigned int uint_t;

// float -> bf16 (RNE)
static __device__ __forceinline__ ushort_t f2bf(float f) {
    uint_t u = __float_as_uint(f);
    u += 0x7FFFu + ((u >> 16) & 1u);
    return (ushort_t)(u >> 16);
}
static __device__ __forceinline__ float bflo(uint_t u) { return __uint_as_float(u << 16); }
static __device__ __forceinline__ float bfhi(uint_t u) { return __uint_as_float(u & 0xFFFF0000u); }

// ---- pass 1: per-block coarse histogram of dst>>7 (int4-vectorized) ----
__global__ void cnt_kernel(const int* __restrict__ ei, int* __restrict__ pcnt) {
    __shared__ int h[NBK];
    for (int i = threadIdx.x; i < NBK; i += blockDim.x) h[i] = 0;
    __syncthreads();
    const int4* d4 = (const int4*)(ei + NE + blockIdx.x * EPB);
    for (int i = threadIdx.x; i < EPB4; i += blockDim.x) {
        int4 d = d4[i];
        atomicAdd(&h[d.x >> 7], 1);
        atomicAdd(&h[d.y >> 7], 1);
        atomicAdd(&h[d.z >> 7], 1);
        atomicAdd(&h[d.w >> 7], 1);
    }
    __syncthreads();
    for (int i = threadIdx.x; i < NBK; i += blockDim.x)
        pcnt[(size_t)i * EBLK + blockIdx.x] = h[i];
}

// ---- pass 2a: per-bucket exclusive scan over the EBLK partials ----
__global__ void bscan_kernel(int* __restrict__ pcnt, int* __restrict__ tot) {
    __shared__ int s[256];
    int k = blockIdx.x, t = threadIdx.x;
    int v = (t < EBLK) ? pcnt[(size_t)k * EBLK + t] : 0;
    s[t] = v;
    __syncthreads();
    for (int off = 1; off < 256; off <<= 1) {
        int add = (t >= off) ? s[t - off] : 0;
        __syncthreads();
        s[t] += add;
        __syncthreads();
    }
    if (t < EBLK) pcnt[(size_t)k * EBLK + t] = s[t] - v;   // exclusive
    if (t == 255) tot[k] = s[255];
}

// ---- pass 2b: exclusive scan of bucket totals -> bbase[0..NBK] ----
__global__ void tscan_kernel(const int* __restrict__ tot, int* __restrict__ bbase) {
    __shared__ int s[512];
    int t = threadIdx.x;
    int v = (t < NBK) ? tot[t] : 0;
    s[t] = v;
    __syncthreads();
    for (int off = 1; off < 512; off <<= 1) {
        int add = (t >= off) ? s[t - off] : 0;
        __syncthreads();
        s[t] += add;
        __syncthreads();
    }
    if (t < NBK) bbase[t] = s[t] - v;
    if (t == NBK - 1) bbase[NBK] = s[t];
}

// ---- pass 3: scatter records {dl:7|src:17, ea} grouped by bucket (int4) ----
__global__ void scatter_kernel(const int* __restrict__ ei, const float* __restrict__ ea,
                               const int* __restrict__ pcnt, const int* __restrict__ bbase,
                               int2* __restrict__ recs) {
    __shared__ int curs[NBK];
    int b = blockIdx.x;
    for (int i = threadIdx.x; i < NBK; i += blockDim.x)
        curs[i] = bbase[i] + pcnt[(size_t)i * EBLK + b];
    __syncthreads();
    int base = b * EPB;
    const int4*   s4 = (const int4*)(ei + base);
    const int4*   d4 = (const int4*)(ei + NE + base);
    const float4* e4 = (const float4*)(ea + base);
    for (int i = threadIdx.x; i < EPB4; i += blockDim.x) {
        int4 ss = s4[i];
        int4 dd = d4[i];
        float4 ee = e4[i];
        int pos, k;
        k = dd.x >> 7; pos = atomicAdd(&curs[k], 1);
        recs[pos] = make_int2(((dd.x & 127) << 17) | ss.x, __float_as_int(ee.x));
        k = dd.y >> 7; pos = atomicAdd(&curs[k], 1);
        recs[pos] = make_int2(((dd.y & 127) << 17) | ss.y, __float_as_int(ee.y));
        k = dd.z >> 7; pos = atomicAdd(&curs[k], 1);
        recs[pos] = make_int2(((dd.z & 127) << 17) | ss.z, __float_as_int(ee.z));
        k = dd.w >> 7; pos = atomicAdd(&curs[k], 1);
        recs[pos] = make_int2(((dd.w & 127) << 17) | ss.w, __float_as_int(ee.w));
    }
}

// ---- merged bucket pass: deg/indeg + in-bucket scan -> offs, dis; then
//      scatter bucket recs to exact per-node CSR {src, ea*dis[dst]} ----
__global__ void binfo2_kernel(const int2* __restrict__ recs, const int* __restrict__ bbase,
                              int* __restrict__ indeg, float* __restrict__ dis,
                              int* __restrict__ offs, int2* __restrict__ csr) {
    __shared__ float deg[NB];
    __shared__ int cnt[NB];
    __shared__ int sc[NB];
    __shared__ int curs[NB];
    __shared__ float wdst[NB];
    int k = blockIdx.x;
    int lo = k * NB;
    int nLoc = min(NB, NN - lo);
    int tid = threadIdx.x;
    for (int i = tid; i < nLoc; i += blockDim.x) { deg[i] = 0.f; cnt[i] = 0; }
    __syncthreads();
    int start = bbase[k], end = bbase[k + 1];
    for (int e = start + tid; e < end; e += blockDim.x) {
        int2 r = recs[e];
        int dl = r.x >> 17;
        atomicAdd(&deg[dl], __int_as_float(r.y));
        atomicAdd(&cnt[dl], 1);
    }
    __syncthreads();
    for (int i = tid; i < nLoc; i += blockDim.x) {
        float d = rsqrtf(deg[i] + 1.0f);
        wdst[i] = d;
        dis[lo + i] = d;
        indeg[lo + i] = cnt[i];
    }
    if (tid < NB) sc[tid] = (tid < nLoc) ? cnt[tid] : 0;
    __syncthreads();
    // inclusive scan over 128 bins
    for (int off = 1; off < NB; off <<= 1) {
        int add = (tid < NB && tid >= off) ? sc[tid - off] : 0;
        __syncthreads();
        if (tid < NB) sc[tid] += add;
        __syncthreads();
    }
    if (tid < nLoc) {
        int ex = start + sc[tid] - cnt[tid];   // exclusive position
        offs[lo + tid] = ex;
        curs[tid] = ex;
    }
    __syncthreads();
    for (int e = start + tid; e < end; e += blockDim.x) {
        int2 r = recs[e];
        int src = r.x & 0x1FFFF;
        int dl = r.x >> 17;
        float pw = __int_as_float(r.y) * wdst[dl];   // ea * dis[dst]
        int pos = atomicAdd(&curs[dl], 1);
        csr[pos] = make_int2(src, __float_as_int(pw));
    }
}

// ---- tiled GEMM: 64 rows x 64 cols per block, X transposed in LDS ----
// Yb[n,HID] = bf16( dis[n] * (X[n,K] @ W[K,HID]) ).  4x4 register tile/thread.
template <int K>
__global__ __launch_bounds__(256) void gemm_kernel(const float* __restrict__ X,
                                                   const float* __restrict__ W,
                                                   const float* __restrict__ dis,
                                                   ushort_t* __restrict__ Yb) {
    __shared__ float w_lds[K * HID];     // [K][64]
    __shared__ float x_lds[K][65];       // transposed [k][row], pad 65
    int tid = threadIdx.x;
    int rowbase = blockIdx.x * 64;
    for (int i = tid; i < K * HID; i += 256) w_lds[i] = W[i];
    for (int i = tid; i < 16 * K; i += 256) {
        int row = i / (K / 4);
        int k4 = i % (K / 4);
        int r = rowbase + row;
        float4 v = (r < NN) ? ((const float4*)(X + (size_t)r * K))[k4]
                            : make_float4(0.f, 0.f, 0.f, 0.f);
        x_lds[k4 * 4 + 0][row] = v.x;
        x_lds[k4 * 4 + 1][row] = v.y;
        x_lds[k4 * 4 + 2][row] = v.z;
        x_lds[k4 * 4 + 3][row] = v.w;
    }
    __syncthreads();
    int c0 = (tid & 15) * 4;
    int r0 = (tid >> 4) * 4;
    float acc[4][4] = {};
#pragma unroll 4
    for (int k = 0; k < K; ++k) {
        float x0 = x_lds[k][r0 + 0];
        float x1 = x_lds[k][r0 + 1];
        float x2 = x_lds[k][r0 + 2];
        float x3 = x_lds[k][r0 + 3];
        float4 wv = *(const float4*)&w_lds[k * HID + c0];
        acc[0][0] += x0 * wv.x; acc[0][1] += x0 * wv.y; acc[0][2] += x0 * wv.z; acc[0][3] += x0 * wv.w;
        acc[1][0] += x1 * wv.x; acc[1][1] += x1 * wv.y; acc[1][2] += x1 * wv.z; acc[1][3] += x1 * wv.w;
        acc[2][0] += x2 * wv.x; acc[2][1] += x2 * wv.y; acc[2][2] += x2 * wv.z; acc[2][3] += x2 * wv.w;
        acc[3][0] += x3 * wv.x; acc[3][1] += x3 * wv.y; acc[3][2] += x3 * wv.z; acc[3][3] += x3 * wv.w;
    }
#pragma unroll
    for (int i = 0; i < 4; ++i) {
        int r = rowbase + r0 + i;
        if (r < NN) {
            float dr = dis[r];
            ushort4 o;
            o.x = f2bf(dr * acc[i][0]); o.y = f2bf(dr * acc[i][1]);
            o.z = f2bf(dr * acc[i][2]); o.w = f2bf(dr * acc[i][3]);
            *(ushort4*)&Yb[(size_t)r * HID + c0] = o;
        }
    }
}

// ---- gather1: h1[node] = relu( agg(A1) + dis*A1[node] + b1 )  (fp32 out) ----
__global__ void gather1_kernel(const int2* __restrict__ csr,
                               const int* __restrict__ offs,
                               const int* __restrict__ indeg,
                               const float* __restrict__ dis,
                               const ushort_t* __restrict__ A1,
                               const float* __restrict__ b1,
                               float* __restrict__ OUT) {
    int node = blockIdx.x * 4 + (threadIdx.x >> 6);
    int lane = threadIdx.x & 63;
    if (node >= NN) return;
    int o  = lane >> 3;
    int cl = lane & 7;
    int start = offs[node];
    int n = indeg[node];
    float a0 = 0.f, a1 = 0.f, a2 = 0.f, a3 = 0.f;
    float a4 = 0.f, a5 = 0.f, a6 = 0.f, a7 = 0.f;
    for (int c = 0; c < n; c += 64) {
        int idx = c + lane;
        int2 rec = (idx < n) ? csr[start + idx] : make_int2(0, 0);  // w=0 pad
        int tmax = min(n - c, 64);
#pragma unroll 2
        for (int t = 0; t * 8 < tmax; ++t) {
            int sl = t * 8 + o;
            int key = __shfl(rec.x, sl, 64);
            float w = __int_as_float(__shfl(rec.y, sl, 64));
            uint4 v = *(const uint4*)(A1 + ((size_t)key << 6) + (cl << 3));
            a0 += w * bflo(v.x); a1 += w * bfhi(v.x);
            a2 += w * bflo(v.y); a3 += w * bfhi(v.y);
            a4 += w * bflo(v.z); a5 += w * bfhi(v.z);
            a6 += w * bflo(v.w); a7 += w * bfhi(v.w);
        }
    }
    a0 += __shfl_xor(a0, 8, 64); a0 += __shfl_xor(a0, 16, 64); a0 += __shfl_xor(a0, 32, 64);
    a1 += __shfl_xor(a1, 8, 64); a1 += __shfl_xor(a1, 16, 64); a1 += __shfl_xor(a1, 32, 64);
    a2 += __shfl_xor(a2, 8, 64); a2 += __shfl_xor(a2, 16, 64); a2 += __shfl_xor(a2, 32, 64);
    a3 += __shfl_xor(a3, 8, 64); a3 += __shfl_xor(a3, 16, 64); a3 += __shfl_xor(a3, 32, 64);
    a4 += __shfl_xor(a4, 8, 64); a4 += __shfl_xor(a4, 16, 64); a4 += __shfl_xor(a4, 32, 64);
    a5 += __shfl_xor(a5, 8, 64); a5 += __shfl_xor(a5, 16, 64); a5 += __shfl_xor(a5, 32, 64);
    a6 += __shfl_xor(a6, 8, 64); a6 += __shfl_xor(a6, 16, 64); a6 += __shfl_xor(a6, 32, 64);
    a7 += __shfl_xor(a7, 8, 64); a7 += __shfl_xor(a7, 16, 64); a7 += __shfl_xor(a7, 32, 64);
    if (o == 0) {
        float d = dis[node];
        uint4 sv = *(const uint4*)(A1 + ((size_t)node << 6) + (cl << 3));
        const float4* bv = (const float4*)(b1 + (cl << 3));
        float4 bA = bv[0], bB = bv[1];
        float o0 = fmaxf(a0 + d * bflo(sv.x) + bA.x, 0.f);
        float o1 = fmaxf(a1 + d * bfhi(sv.x) + bA.y, 0.f);
        float o2 = fmaxf(a2 + d * bflo(sv.y) + bA.z, 0.f);
        float o3 = fmaxf(a3 + d * bfhi(sv.y) + bA.w, 0.f);
        float o4 = fmaxf(a4 + d * bflo(sv.z) + bB.x, 0.f);
        float o5 = fmaxf(a5 + d * bfhi(sv.z) + bB.y, 0.f);
        float o6 = fmaxf(a6 + d * bflo(sv.w) + bB.z, 0.f);
        float o7 = fmaxf(a7 + d * bfhi(sv.w) + bB.w, 0.f);
        float* op = &OUT[((size_t)node << 6) + (cl << 3)];
        *(float4*)op       = make_float4(o0, o1, o2, o3);
        *(float4*)(op + 4) = make_float4(o4, o5, o6, o7);
    }
}

// ---- gather2 + fused head: nodeval[node] = dot(agg(A2)+self+b2, Wlin) ----
__global__ void gather2_kernel(const int2* __restrict__ csr,
                               const int* __restrict__ offs,
                               const int* __restrict__ indeg,
                               const float* __restrict__ dis,
                               const ushort_t* __restrict__ A2,
                               const float* __restrict__ b2,
                               const float* __restrict__ Wlin,
                               float* __restrict__ nodeval) {
    int node = blockIdx.x * 4 + (threadIdx.x >> 6);
    int lane = threadIdx.x & 63;
    if (node >= NN) return;
    int o  = lane >> 3;
    int cl = lane & 7;
    int start = offs[node];
    int n = indeg[node];
    float a0 = 0.f, a1 = 0.f, a2 = 0.f, a3 = 0.f;
    float a4 = 0.f, a5 = 0.f, a6 = 0.f, a7 = 0.f;
    for (int c = 0; c < n; c += 64) {
        int idx = c + lane;
        int2 rec = (idx < n) ? csr[start + idx] : make_int2(0, 0);
        int tmax = min(n - c, 64);
#pragma unroll 2
        for (int t = 0; t * 8 < tmax; ++t) {
            int sl = t * 8 + o;
            int key = __shfl(rec.x, sl, 64);
            float w = __int_as_float(__shfl(rec.y, sl, 64));
            uint4 v = *(const uint4*)(A2 + ((size_t)key << 6) + (cl << 3));
            a0 += w * bflo(v.x); a1 += w * bfhi(v.x);
            a2 += w * bflo(v.y); a3 += w * bfhi(v.y);
            a4 += w * bflo(v.z); a5 += w * bfhi(v.z);
            a6 += w * bflo(v.w); a7 += w * bfhi(v.w);
        }
    }
    a0 += __shfl_xor(a0, 8, 64); a0 += __shfl_xor(a0, 16, 64); a0 += __shfl_xor(a0, 32, 64);
    a1 += __shfl_xor(a1, 8, 64); a1 += __shfl_xor(a1, 16, 64); a1 += __shfl_xor(a1, 32, 64);
    a2 += __shfl_xor(a2, 8, 64); a2 += __shfl_xor(a2, 16, 64); a2 += __shfl_xor(a2, 32, 64);
    a3 += __shfl_xor(a3, 8, 64); a3 += __shfl_xor(a3, 16, 64); a3 += __shfl_xor(a3, 32, 64);
    a4 += __shfl_xor(a4, 8, 64); a4 += __shfl_xor(a4, 16, 64); a4 += __shfl_xor(a4, 32, 64);
    a5 += __shfl_xor(a5, 8, 64); a5 += __shfl_xor(a5, 16, 64); a5 += __shfl_xor(a5, 32, 64);
    a6 += __shfl_xor(a6, 8, 64); a6 += __shfl_xor(a6, 16, 64); a6 += __shfl_xor(a6, 32, 64);
    a7 += __shfl_xor(a7, 8, 64); a7 += __shfl_xor(a7, 16, 64); a7 += __shfl_xor(a7, 32, 64);
    float d = dis[node];
    uint4 sv = *(const uint4*)(A2 + ((size_t)node << 6) + (cl << 3));
    const float4* bv = (const float4*)(b2 + (cl << 3));
    float4 bA = bv[0], bB = bv[1];
    const float4* wv = (const float4*)(Wlin + (cl << 3));
    float4 wA = wv[0], wB = wv[1];
    float dot = (a0 + d * bflo(sv.x) + bA.x) * wA.x
              + (a1 + d * bfhi(sv.x) + bA.y) * wA.y
              + (a2 + d * bflo(sv.y) + bA.z) * wA.z
              + (a3 + d * bfhi(sv.y) + bA.w) * wA.w
              + (a4 + d * bflo(sv.z) + bB.x) * wB.x
              + (a5 + d * bfhi(sv.z) + bB.y) * wB.y
              + (a6 + d * bflo(sv.w) + bB.z) * wB.z
              + (a7 + d * bfhi(sv.w) + bB.w) * wB.w;
    dot += __shfl_xor(dot, 1, 64);
    dot += __shfl_xor(dot, 2, 64);
    dot += __shfl_xor(dot, 4, 64);
    if (lane == 0) nodeval[node] = dot;
}

// out[g] = (sum of nodeval in batch range g)/cnt + blin   (1 block/graph)
__global__ void pool_final_kernel(const float* __restrict__ nodeval,
                                  const int* __restrict__ batch,
                                  const float* __restrict__ blin,
                                  float* __restrict__ out) {
    __shared__ int bnd[2];
    __shared__ float red[4];
    int g = blockIdx.x;
    if (threadIdx.x < 2) {
        int target = g + threadIdx.x;
        int lo = 0, hi = NN;
        while (lo < hi) {
            int mid = (lo + hi) >> 1;
            if (batch[mid] < target) lo = mid + 1; else hi = mid;
        }
        bnd[threadIdx.x] = lo;
    }
    __syncthreads();
    int s = bnd[0], e = bnd[1];
    float a = 0.f;
    for (int i = s + threadIdx.x; i < e; i += 256) a += nodeval[i];
    for (int off = 32; off > 0; off >>= 1) a += __shfl_down(a, off, 64);
    int lane = threadIdx.x & 63;
    int wv = threadIdx.x >> 6;
    if (lane == 0) red[wv] = a;
    __syncthreads();
    if (threadIdx.x == 0) {
        float t = red[0] + red[1] + red[2] + red[3];
        out[g] = t / fmaxf((float)(e - s), 1.0f) + blin[0];
    }
}

extern "C" void kernel_launch(void* const* d_in, const int* in_sizes, int n_in,
                              void* d_out, int out_size, void* d_ws, size_t ws_size,
                              hipStream_t stream) {
    const float* x     = (const float*)d_in[0];
    const int*   ei    = (const int*)d_in[1];
    const float* ea    = (const float*)d_in[2];
    const int*   batch = (const int*)d_in[3];
    const float* W1    = (const float*)d_in[4];
    const float* b1    = (const float*)d_in[5];
    const float* W2    = (const float*)d_in[6];
    const float* b2    = (const float*)d_in[7];
    const float* Wlin  = (const float*)d_in[8];
    const float* blin  = (const float*)d_in[9];
    float*       out   = (float*)d_out;

    char* ws = (char*)d_ws;
    auto alloc = [&](size_t bytes) {
        void* p = (void*)ws;
        ws += (bytes + 255) / 256 * 256;
        return p;
    };
    float*    dis     = (float*)alloc((size_t)NN * 4);
    int*      indeg   = (int*)alloc((size_t)NN * 4);
    int*      offs    = (int*)alloc((size_t)NN * 4);
    int*      pcnt    = (int*)alloc((size_t)NBK * EBLK * 4);
    int*      tot     = (int*)alloc((size_t)NBK * 4);
    int*      bbase   = (int*)alloc((size_t)(NBK + 1) * 4);
    int2*     recs    = (int2*)alloc((size_t)NE * 8);   // dead after binfo2 -> A1|A2
    int2*     csr     = (int2*)alloc((size_t)NE * 8);   // {src, ea*dis[dst]}
    float*    B       = (float*)alloc((size_t)NN * HID * 4);  // fp32 h1
    float*    nodeval = (float*)alloc((size_t)NN * 4);
    ushort_t* A1      = (ushort_t*)recs;                      // bf16 dis*(x@W1)
    ushort_t* A2      = (ushort_t*)recs + (size_t)NN * HID;   // bf16 dis*(h1@W2)

    // two-level bucket sort of edges by dst (no global atomics)
    cnt_kernel<<<EBLK, 256, 0, stream>>>(ei, pcnt);
    bscan_kernel<<<NBK, 256, 0, stream>>>(pcnt, tot);
    tscan_kernel<<<1, 512, 0, stream>>>(tot, bbase);
    scatter_kernel<<<EBLK, 256, 0, stream>>>(ei, ea, pcnt, bbase, recs);
    binfo2_kernel<<<NBK, 256, 0, stream>>>(recs, bbase, indeg, dis, offs, csr);

    // conv1: A1 = bf16(dis*(x@W1));  h1 = relu(agg(A1)+self+b1)  (fp32)
    gemm_kernel<IN_DIM><<<(NN + 63) / 64, 256, 0, stream>>>(x, W1, dis, A1);
    gather1_kernel<<<(NN + 3) / 4, 256, 0, stream>>>(csr, offs, indeg, dis, A1, b1, B);

    // conv2: A2 = bf16(dis*(h1@W2));  gather2 + head -> nodeval
    gemm_kernel<HID><<<(NN + 63) / 64, 256, 0, stream>>>(B, W2, dis, A2);
    gather2_kernel<<<(NN + 3) / 4, 256, 0, stream>>>(csr, offs, indeg, dis, A2, b2,
                                                     Wlin, nodeval);

    // segmented mean + blin
    pool_final_kernel<<<NG, 256, 0, stream>>>(nodeval, batch, blin, out);
}

// Round 19
// 148.517 us; speedup vs baseline: 2.6987x; 1.0351x over previous
//
#include <hip/hip_runtime.h>

#define NN 50000
#define NE 1600000
#define NG 512
#define IN_DIM 128
#define HID 64

#define NB 128                       // nodes per bucket
#define NBK ((NN + NB - 1) / NB)     // 391 buckets
#define EBLK 250                     // edge-pass blocks
#define EPB (NE / EBLK)              // 6400 edges per block (div by 4)
#define EPB4 (EPB / 4)               // 1600 int4 groups
#define BCAP 6144                    // staged records per bucket (mean 4096)

typedef unsigned short ushort_t;
typedef unsigned int uint_t;

// float -> bf16 (RNE)
static __device__ __forceinline__ ushort_t f2bf(float f) {
    uint_t u = __float_as_uint(f);
    u += 0x7FFFu + ((u >> 16) & 1u);
    return (ushort_t)(u >> 16);
}
static __device__ __forceinline__ float bflo(uint_t u) { return __uint_as_float(u << 16); }
static __device__ __forceinline__ float bfhi(uint_t u) { return __uint_as_float(u & 0xFFFF0000u); }

// ---- pass 1: per-block coarse histogram of dst>>7 (int4-vectorized) ----
__global__ void cnt_kernel(const int* __restrict__ ei, int* __restrict__ pcnt) {
    __shared__ int h[NBK];
    for (int i = threadIdx.x; i < NBK; i += blockDim.x) h[i] = 0;
    __syncthreads();
    const int4* d4 = (const int4*)(ei + NE + blockIdx.x * EPB);
    for (int i = threadIdx.x; i < EPB4; i += blockDim.x) {
        int4 d = d4[i];
        atomicAdd(&h[d.x >> 7], 1);
        atomicAdd(&h[d.y >> 7], 1);
        atomicAdd(&h[d.z >> 7], 1);
        atomicAdd(&h[d.w >> 7], 1);
    }
    __syncthreads();
    for (int i = threadIdx.x; i < NBK; i += blockDim.x)
        pcnt[(size_t)i * EBLK + blockIdx.x] = h[i];
}

// ---- pass 2a: per-bucket exclusive scan over the EBLK partials ----
__global__ void bscan_kernel(int* __restrict__ pcnt, int* __restrict__ tot) {
    __shared__ int s[256];
    int k = blockIdx.x, t = threadIdx.x;
    int v = (t < EBLK) ? pcnt[(size_t)k * EBLK + t] : 0;
    s[t] = v;
    __syncthreads();
    for (int off = 1; off < 256; off <<= 1) {
        int add = (t >= off) ? s[t - off] : 0;
        __syncthreads();
        s[t] += add;
        __syncthreads();
    }
    if (t < EBLK) pcnt[(size_t)k * EBLK + t] = s[t] - v;   // exclusive
    if (t == 255) tot[k] = s[255];
}

// ---- pass 2b: exclusive scan of bucket totals -> bbase[0..NBK] ----
__global__ void tscan_kernel(const int* __restrict__ tot, int* __restrict__ bbase) {
    __shared__ int s[512];
    int t = threadIdx.x;
    int v = (t < NBK) ? tot[t] : 0;
    s[t] = v;
    __syncthreads();
    for (int off = 1; off < 512; off <<= 1) {
        int add = (t >= off) ? s[t - off] : 0;
        __syncthreads();
        s[t] += add;
        __syncthreads();
    }
    if (t < NBK) bbase[t] = s[t] - v;
    if (t == NBK - 1) bbase[NBK] = s[t];
}

// ---- pass 3: scatter records {dl:7|src:17, ea} grouped by bucket (int4) ----
__global__ void scatter_kernel(const int* __restrict__ ei, const float* __restrict__ ea,
                               const int* __restrict__ pcnt, const int* __restrict__ bbase,
                               int2* __restrict__ recs) {
    __shared__ int curs[NBK];
    int b = blockIdx.x;
    for (int i = threadIdx.x; i < NBK; i += blockDim.x)
        curs[i] = bbase[i] + pcnt[(size_t)i * EBLK + b];
    __syncthreads();
    int base = b * EPB;
    const int4*   s4 = (const int4*)(ei + base);
    const int4*   d4 = (const int4*)(ei + NE + base);
    const float4* e4 = (const float4*)(ea + base);
    for (int i = threadIdx.x; i < EPB4; i += blockDim.x) {
        int4 ss = s4[i];
        int4 dd = d4[i];
        float4 ee = e4[i];
        int pos, k;
        k = dd.x >> 7; pos = atomicAdd(&curs[k], 1);
        recs[pos] = make_int2(((dd.x & 127) << 17) | ss.x, __float_as_int(ee.x));
        k = dd.y >> 7; pos = atomicAdd(&curs[k], 1);
        recs[pos] = make_int2(((dd.y & 127) << 17) | ss.y, __float_as_int(ee.y));
        k = dd.z >> 7; pos = atomicAdd(&curs[k], 1);
        recs[pos] = make_int2(((dd.z & 127) << 17) | ss.z, __float_as_int(ee.z));
        k = dd.w >> 7; pos = atomicAdd(&curs[k], 1);
        recs[pos] = make_int2(((dd.w & 127) << 17) | ss.w, __float_as_int(ee.w));
    }
}

// ---- merged bucket pass: deg + in-bucket scan -> offs (NN+1), dis; then
//      distribute recs into LDS stage and flush csr contiguously ----
__global__ void binfo2_kernel(const int2* __restrict__ recs, const int* __restrict__ bbase,
                              float* __restrict__ dis, int* __restrict__ offs,
                              int2* __restrict__ csr) {
    __shared__ float deg[NB];
    __shared__ int cnt[NB];
    __shared__ int sc[NB];
    __shared__ int curs[NB];
    __shared__ float wdst[NB];
    __shared__ int2 stage[BCAP];     // 48 KB
    int k = blockIdx.x;
    int lo = k * NB;
    int nLoc = min(NB, NN - lo);
    int tid = threadIdx.x;
    for (int i = tid; i < nLoc; i += 256) { deg[i] = 0.f; cnt[i] = 0; }
    __syncthreads();
    int start = bbase[k], end = bbase[k + 1];
    int m = end - start;
    for (int e = tid; e < m; e += 256) {
        int2 r = recs[start + e];
        int dl = r.x >> 17;
        atomicAdd(&deg[dl], __int_as_float(r.y));
        atomicAdd(&cnt[dl], 1);
    }
    __syncthreads();
    for (int i = tid; i < nLoc; i += 256) {
        float d = rsqrtf(deg[i] + 1.0f);
        wdst[i] = d;
        dis[lo + i] = d;
    }
    if (tid < NB) sc[tid] = (tid < nLoc) ? cnt[tid] : 0;
    __syncthreads();
    // inclusive scan over 128 bins
    for (int off = 1; off < NB; off <<= 1) {
        int add = (tid < NB && tid >= off) ? sc[tid - off] : 0;
        __syncthreads();
        if (tid < NB) sc[tid] += add;
        __syncthreads();
    }
    if (tid < nLoc) {
        int exRel = sc[tid] - cnt[tid];        // bucket-relative exclusive pos
        offs[lo + tid] = start + exRel;
        curs[tid] = exRel;
    }
    if (k == NBK - 1 && tid == 0) offs[NN] = end;   // = NE
    __syncthreads();
    if (m <= BCAP) {
        for (int e = tid; e < m; e += 256) {
            int2 r = recs[start + e];
            int src = r.x & 0x1FFFF;
            int dl = r.x >> 17;
            float pw = __int_as_float(r.y) * wdst[dl];   // ea * dis[dst]
            int pos = atomicAdd(&curs[dl], 1);
            stage[pos] = make_int2(src, __float_as_int(pw));
        }
        __syncthreads();
        for (int e = tid; e < m; e += 256)            // coalesced flush
            csr[start + e] = stage[e];
    } else {                                          // fallback (never expected)
        for (int e = tid; e < m; e += 256) {
            int2 r = recs[start + e];
            int src = r.x & 0x1FFFF;
            int dl = r.x >> 17;
            float pw = __int_as_float(r.y) * wdst[dl];
            int pos = atomicAdd(&curs[dl], 1);
            csr[start + pos] = make_int2(src, __float_as_int(pw));
        }
    }
}

// ---- tiled GEMM (fp32 input): Yb[n,HID] = bf16( dis[n] * (X @ W) ) ----
template <int K>
__global__ __launch_bounds__(256) void gemm_kernel(const float* __restrict__ X,
                                                   const float* __restrict__ W,
                                                   const float* __restrict__ dis,
                                                   ushort_t* __restrict__ Yb) {
    __shared__ float w_lds[K * HID];     // [K][64]
    __shared__ float x_lds[K][65];       // transposed [k][row], pad 65
    int tid = threadIdx.x;
    int rowbase = blockIdx.x * 64;
    for (int i = tid; i < K * HID; i += 256) w_lds[i] = W[i];
    for (int i = tid; i < 16 * K; i += 256) {
        int row = i / (K / 4);
        int k4 = i % (K / 4);
        int r = rowbase + row;
        float4 v = (r < NN) ? ((const float4*)(X + (size_t)r * K))[k4]
                            : make_float4(0.f, 0.f, 0.f, 0.f);
        x_lds[k4 * 4 + 0][row] = v.x;
        x_lds[k4 * 4 + 1][row] = v.y;
        x_lds[k4 * 4 + 2][row] = v.z;
        x_lds[k4 * 4 + 3][row] = v.w;
    }
    __syncthreads();
    int c0 = (tid & 15) * 4;
    int r0 = (tid >> 4) * 4;
    float acc[4][4] = {};
#pragma unroll 4
    for (int k = 0; k < K; ++k) {
        float x0 = x_lds[k][r0 + 0];
        float x1 = x_lds[k][r0 + 1];
        float x2 = x_lds[k][r0 + 2];
        float x3 = x_lds[k][r0 + 3];
        float4 wv = *(const float4*)&w_lds[k * HID + c0];
        acc[0][0] += x0 * wv.x; acc[0][1] += x0 * wv.y; acc[0][2] += x0 * wv.z; acc[0][3] += x0 * wv.w;
        acc[1][0] += x1 * wv.x; acc[1][1] += x1 * wv.y; acc[1][2] += x1 * wv.z; acc[1][3] += x1 * wv.w;
        acc[2][0] += x2 * wv.x; acc[2][1] += x2 * wv.y; acc[2][2] += x2 * wv.z; acc[2][3] += x2 * wv.w;
        acc[3][0] += x3 * wv.x; acc[3][1] += x3 * wv.y; acc[3][2] += x3 * wv.z; acc[3][3] += x3 * wv.w;
    }
#pragma unroll
    for (int i = 0; i < 4; ++i) {
        int r = rowbase + r0 + i;
        if (r < NN) {
            float dr = dis[r];
            ushort4 o;
            o.x = f2bf(dr * acc[i][0]); o.y = f2bf(dr * acc[i][1]);
            o.z = f2bf(dr * acc[i][2]); o.w = f2bf(dr * acc[i][3]);
            *(ushort4*)&Yb[(size_t)r * HID + c0] = o;
        }
    }
}

// ---- tiled GEMM (bf16 input, K=64): Yb = bf16( dis * (Xb @ W) ) ----
__global__ __launch_bounds__(256) void gemm2b_kernel(const ushort_t* __restrict__ Xb,
                                                     const float* __restrict__ W,
                                                     const float* __restrict__ dis,
                                                     ushort_t* __restrict__ Yb) {
    __shared__ float w_lds[HID * HID];
    __shared__ float x_lds[HID][65];
    int tid = threadIdx.x;
    int rowbase = blockIdx.x * 64;
    for (int i = tid; i < HID * HID; i += 256) w_lds[i] = W[i];
    for (int i = tid; i < 512; i += 256) {       // 64 rows x 8 groups (8 bf16)
        int row = i >> 3;
        int g = i & 7;
        int r = rowbase + row;
        uint4 v = make_uint4(0u, 0u, 0u, 0u);
        if (r < NN) v = ((const uint4*)(Xb + ((size_t)r << 6)))[g];
        int k0 = g * 8;
        x_lds[k0 + 0][row] = bflo(v.x); x_lds[k0 + 1][row] = bfhi(v.x);
        x_lds[k0 + 2][row] = bflo(v.y); x_lds[k0 + 3][row] = bfhi(v.y);
        x_lds[k0 + 4][row] = bflo(v.z); x_lds[k0 + 5][row] = bfhi(v.z);
        x_lds[k0 + 6][row] = bflo(v.w); x_lds[k0 + 7][row] = bfhi(v.w);
    }
    __syncthreads();
    int c0 = (tid & 15) * 4;
    int r0 = (tid >> 4) * 4;
    float acc[4][4] = {};
#pragma unroll 4
    for (int k = 0; k < HID; ++k) {
        float x0 = x_lds[k][r0 + 0];
        float x1 = x_lds[k][r0 + 1];
        float x2 = x_lds[k][r0 + 2];
        float x3 = x_lds[k][r0 + 3];
        float4 wv = *(const float4*)&w_lds[k * HID + c0];
        acc[0][0] += x0 * wv.x; acc[0][1] += x0 * wv.y; acc[0][2] += x0 * wv.z; acc[0][3] += x0 * wv.w;
        acc[1][0] += x1 * wv.x; acc[1][1] += x1 * wv.y; acc[1][2] += x1 * wv.z; acc[1][3] += x1 * wv.w;
        acc[2][0] += x2 * wv.x; acc[2][1] += x2 * wv.y; acc[2][2] += x2 * wv.z; acc[2][3] += x2 * wv.w;
        acc[3][0] += x3 * wv.x; acc[3][1] += x3 * wv.y; acc[3][2] += x3 * wv.z; acc[3][3] += x3 * wv.w;
    }
#pragma unroll
    for (int i = 0; i < 4; ++i) {
        int r = rowbase + r0 + i;
        if (r < NN) {
            float dr = dis[r];
            ushort4 o;
            o.x = f2bf(dr * acc[i][0]); o.y = f2bf(dr * acc[i][1]);
            o.z = f2bf(dr * acc[i][2]); o.w = f2bf(dr * acc[i][3]);
            *(ushort4*)&Yb[(size_t)r * HID + c0] = o;
        }
    }
}

// ---- gather1: H1b[node] = bf16(relu( agg(A1) + dis*A1[node] + b1 )) ----
__global__ void gather1_kernel(const int2* __restrict__ csr,
                               const int* __restrict__ offs,
                               const float* __restrict__ dis,
                               const ushort_t* __restrict__ A1,
                               const float* __restrict__ b1,
                               ushort_t* __restrict__ H1b) {
    int node = blockIdx.x * 4 + (threadIdx.x >> 6);
    int lane = threadIdx.x & 63;
    if (node >= NN) return;
    int o  = lane >> 3;
    int cl = lane & 7;
    int start = offs[node];
    int n = offs[node + 1] - start;
    float a0 = 0.f, a1 = 0.f, a2 = 0.f, a3 = 0.f;
    float a4 = 0.f, a5 = 0.f, a6 = 0.f, a7 = 0.f;
    for (int c = 0; c < n; c += 64) {
        int idx = c + lane;
        int2 rec = (idx < n) ? csr[start + idx] : make_int2(0, 0);  // w=0 pad
        int tmax = min(n - c, 64);
#pragma unroll 2
        for (int t = 0; t * 8 < tmax; ++t) {
            int sl = t * 8 + o;
            int key = __shfl(rec.x, sl, 64);
            float w = __int_as_float(__shfl(rec.y, sl, 64));
            uint4 v = *(const uint4*)(A1 + ((size_t)key << 6) + (cl << 3));
            a0 += w * bflo(v.x); a1 += w * bfhi(v.x);
            a2 += w * bflo(v.y); a3 += w * bfhi(v.y);
            a4 += w * bflo(v.z); a5 += w * bfhi(v.z);
            a6 += w * bflo(v.w); a7 += w * bfhi(v.w);
        }
    }
    a0 += __shfl_xor(a0, 8, 64); a0 += __shfl_xor(a0, 16, 64); a0 += __shfl_xor(a0, 32, 64);
    a1 += __shfl_xor(a1, 8, 64); a1 += __shfl_xor(a1, 16, 64); a1 += __shfl_xor(a1, 32, 64);
    a2 += __shfl_xor(a2, 8, 64); a2 += __shfl_xor(a2, 16, 64); a2 += __shfl_xor(a2, 32, 64);
    a3 += __shfl_xor(a3, 8, 64); a3 += __shfl_xor(a3, 16, 64); a3 += __shfl_xor(a3, 32, 64);
    a4 += __shfl_xor(a4, 8, 64); a4 += __shfl_xor(a4, 16, 64); a4 += __shfl_xor(a4, 32, 64);
    a5 += __shfl_xor(a5, 8, 64); a5 += __shfl_xor(a5, 16, 64); a5 += __shfl_xor(a5, 32, 64);
    a6 += __shfl_xor(a6, 8, 64); a6 += __shfl_xor(a6, 16, 64); a6 += __shfl_xor(a6, 32, 64);
    a7 += __shfl_xor(a7, 8, 64); a7 += __shfl_xor(a7, 16, 64); a7 += __shfl_xor(a7, 32, 64);
    if (o == 0) {
        float d = dis[node];
        uint4 sv = *(const uint4*)(A1 + ((size_t)node << 6) + (cl << 3));
        const float4* bv = (const float4*)(b1 + (cl << 3));
        float4 bA = bv[0], bB = bv[1];
        float o0 = fmaxf(a0 + d * bflo(sv.x) + bA.x, 0.f);
        float o1 = fmaxf(a1 + d * bfhi(sv.x) + bA.y, 0.f);
        float o2 = fmaxf(a2 + d * bflo(sv.y) + bA.z, 0.f);
        float o3 = fmaxf(a3 + d * bfhi(sv.y) + bA.w, 0.f);
        float o4 = fmaxf(a4 + d * bflo(sv.z) + bB.x, 0.f);
        float o5 = fmaxf(a5 + d * bfhi(sv.z) + bB.y, 0.f);
        float o6 = fmaxf(a6 + d * bflo(sv.w) + bB.z, 0.f);
        float o7 = fmaxf(a7 + d * bfhi(sv.w) + bB.w, 0.f);
        uint4 ov;
        ov.x = (uint_t)f2bf(o0) | ((uint_t)f2bf(o1) << 16);
        ov.y = (uint_t)f2bf(o2) | ((uint_t)f2bf(o3) << 16);
        ov.z = (uint_t)f2bf(o4) | ((uint_t)f2bf(o5) << 16);
        ov.w = (uint_t)f2bf(o6) | ((uint_t)f2bf(o7) << 16);
        *(uint4*)(H1b + ((size_t)node << 6) + (cl << 3)) = ov;
    }
}

// ---- gather2 + fused head: nodeval[node] = dot(agg(A2)+self+b2, Wlin) ----
__global__ void gather2_kernel(const int2* __restrict__ csr,
                               const int* __restrict__ offs,
                               const float* __restrict__ dis,
                               const ushort_t* __restrict__ A2,
                               const float* __restrict__ b2,
                               const float* __restrict__ Wlin,
                               float* __restrict__ nodeval) {
    int node = blockIdx.x * 4 + (threadIdx.x >> 6);
    int lane = threadIdx.x & 63;
    if (node >= NN) return;
    int o  = lane >> 3;
    int cl = lane & 7;
    int start = offs[node];
    int n = offs[node + 1] - start;
    float a0 = 0.f, a1 = 0.f, a2 = 0.f, a3 = 0.f;
    float a4 = 0.f, a5 = 0.f, a6 = 0.f, a7 = 0.f;
    for (int c = 0; c < n; c += 64) {
        int idx = c + lane;
        int2 rec = (idx < n) ? csr[start + idx] : make_int2(0, 0);
        int tmax = min(n - c, 64);
#pragma unroll 2
        for (int t = 0; t * 8 < tmax; ++t) {
            int sl = t * 8 + o;
            int key = __shfl(rec.x, sl, 64);
            float w = __int_as_float(__shfl(rec.y, sl, 64));
            uint4 v = *(const uint4*)(A2 + ((size_t)key << 6) + (cl << 3));
            a0 += w * bflo(v.x); a1 += w * bfhi(v.x);
            a2 += w * bflo(v.y); a3 += w * bfhi(v.y);
            a4 += w * bflo(v.z); a5 += w * bfhi(v.z);
            a6 += w * bflo(v.w); a7 += w * bfhi(v.w);
        }
    }
    a0 += __shfl_xor(a0, 8, 64); a0 += __shfl_xor(a0, 16, 64); a0 += __shfl_xor(a0, 32, 64);
    a1 += __shfl_xor(a1, 8, 64); a1 += __shfl_xor(a1, 16, 64); a1 += __shfl_xor(a1, 32, 64);
    a2 += __shfl_xor(a2, 8, 64); a2 += __shfl_xor(a2, 16, 64); a2 += __shfl_xor(a2, 32, 64);
    a3 += __shfl_xor(a3, 8, 64); a3 += __shfl_xor(a3, 16, 64); a3 += __shfl_xor(a3, 32, 64);
    a4 += __shfl_xor(a4, 8, 64); a4 += __shfl_xor(a4, 16, 64); a4 += __shfl_xor(a4, 32, 64);
    a5 += __shfl_xor(a5, 8, 64); a5 += __shfl_xor(a5, 16, 64); a5 += __shfl_xor(a5, 32, 64);
    a6 += __shfl_xor(a6, 8, 64); a6 += __shfl_xor(a6, 16, 64); a6 += __shfl_xor(a6, 32, 64);
    a7 += __shfl_xor(a7, 8, 64); a7 += __shfl_xor(a7, 16, 64); a7 += __shfl_xor(a7, 32, 64);
    float d = dis[node];
    uint4 sv = *(const uint4*)(A2 + ((size_t)node << 6) + (cl << 3));
    const float4* bv = (const float4*)(b2 + (cl << 3));
    float4 bA = bv[0], bB = bv[1];
    const float4* wv = (const float4*)(Wlin + (cl << 3));
    float4 wA = wv[0], wB = wv[1];
    float dot = (a0 + d * bflo(sv.x) + bA.x) * wA.x
              + (a1 + d * bfhi(sv.x) + bA.y) * wA.y
              + (a2 + d * bflo(sv.y) + bA.z) * wA.z
              + (a3 + d * bfhi(sv.y) + bA.w) * wA.w
              + (a4 + d * bflo(sv.z) + bB.x) * wB.x
              + (a5 + d * bfhi(sv.z) + bB.y) * wB.y
              + (a6 + d * bflo(sv.w) + bB.z) * wB.z
              + (a7 + d * bfhi(sv.w) + bB.w) * wB.w;
    dot += __shfl_xor(dot, 1, 64);
    dot += __shfl_xor(dot, 2, 64);
    dot += __shfl_xor(dot, 4, 64);
    if (lane == 0) nodeval[node] = dot;
}

// out[g] = (sum of nodeval in batch range g)/cnt + blin   (1 block/graph)
__global__ void pool_final_kernel(const float* __restrict__ nodeval,
                                  const int* __restrict__ batch,
                                  const float* __restrict__ blin,
                                  float* __restrict__ out) {
    __shared__ int bnd[2];
    __shared__ float red[4];
    int g = blockIdx.x;
    if (threadIdx.x < 2) {
        int target = g + threadIdx.x;
        int lo = 0, hi = NN;
        while (lo < hi) {
            int mid = (lo + hi) >> 1;
            if (batch[mid] < target) lo = mid + 1; else hi = mid;
        }
        bnd[threadIdx.x] = lo;
    }
    __syncthreads();
    int s = bnd[0], e = bnd[1];
    float a = 0.f;
    for (int i = s + threadIdx.x; i < e; i += 256) a += nodeval[i];
    for (int off = 32; off > 0; off >>= 1) a += __shfl_down(a, off, 64);
    int lane = threadIdx.x & 63;
    int wv = threadIdx.x >> 6;
    if (lane == 0) red[wv] = a;
    __syncthreads();
    if (threadIdx.x == 0) {
        float t = red[0] + red[1] + red[2] + red[3];
        out[g] = t / fmaxf((float)(e - s), 1.0f) + blin[0];
    }
}

extern "C" void kernel_launch(void* const* d_in, const int* in_sizes, int n_in,
                              void* d_out, int out_size, void* d_ws, size_t ws_size,
                              hipStream_t stream) {
    const float* x     = (const float*)d_in[0];
    const int*   ei    = (const int*)d_in[1];
    const float* ea    = (const float*)d_in[2];
    const int*   batch = (const int*)d_in[3];
    const float* W1    = (const float*)d_in[4];
    const float* b1    = (const float*)d_in[5];
    const float* W2    = (const float*)d_in[6];
    const float* b2    = (const float*)d_in[7];
    const float* Wlin  = (const float*)d_in[8];
    const float* blin  = (const float*)d_in[9];
    float*       out   = (float*)d_out;

    char* ws = (char*)d_ws;
    auto alloc = [&](size_t bytes) {
        void* p = (void*)ws;
        ws += (bytes + 255) / 256 * 256;
        return p;
    };
    float*    dis     = (float*)alloc((size_t)NN * 4);
    int*      offs    = (int*)alloc((size_t)(NN + 1) * 4);
    int*      pcnt    = (int*)alloc((size_t)NBK * EBLK * 4);
    int*      tot     = (int*)alloc((size_t)NBK * 4);
    int*      bbase   = (int*)alloc((size_t)(NBK + 1) * 4);
    int2*     recs    = (int2*)alloc((size_t)NE * 8);   // dead after binfo2 -> A1|A2
    int2*     csr     = (int2*)alloc((size_t)NE * 8);   // {src, ea*dis[dst]}
    ushort_t* H1b     = (ushort_t*)alloc((size_t)NN * HID * 2);  // bf16 h1
    float*    nodeval = (float*)alloc((size_t)NN * 4);
    ushort_t* A1      = (ushort_t*)recs;                      // bf16 dis*(x@W1)
    ushort_t* A2      = (ushort_t*)recs + (size_t)NN * HID;   // bf16 dis*(h1@W2)

    // two-level bucket sort of edges by dst (no global atomics)
    cnt_kernel<<<EBLK, 256, 0, stream>>>(ei, pcnt);
    bscan_kernel<<<NBK, 256, 0, stream>>>(pcnt, tot);
    tscan_kernel<<<1, 512, 0, stream>>>(tot, bbase);
    scatter_kernel<<<EBLK, 256, 0, stream>>>(ei, ea, pcnt, bbase, recs);
    binfo2_kernel<<<NBK, 256, 0, stream>>>(recs, bbase, dis, offs, csr);

    // conv1: A1 = bf16(dis*(x@W1));  H1b = bf16(relu(agg(A1)+self+b1))
    gemm_kernel<IN_DIM><<<(NN + 63) / 64, 256, 0, stream>>>(x, W1, dis, A1);
    gather1_kernel<<<(NN + 3) / 4, 256, 0, stream>>>(csr, offs, dis, A1, b1, H1b);

    // conv2: A2 = bf16(dis*(H1b@W2));  gather2 + head -> nodeval
    gemm2b_kernel<<<(NN + 63) / 64, 256, 0, stream>>>(H1b, W2, dis, A2);
    gather2_kernel<<<(NN + 3) / 4, 256, 0, stream>>>(csr, offs, dis, A2, b2,
                                                     Wlin, nodeval);

    // segmented mean + blin
    pool_final_kernel<<<NG, 256, 0, stream>>>(nodeval, batch, blin, out);
}